// Round 1
// baseline (1884.902 us; speedup 1.0000x reference)
//
#include <hip/hip_runtime.h>

#define NN 16384
#define DIN 128
#define DH 16
#define DOUT 4

// ---------------------------------------------------------------------------
// Kernel 1: B1 = X @ W1   [N,16]   (tiny: 67 MFLOP, ~3 us) — unchanged.
// ---------------------------------------------------------------------------
__global__ __launch_bounds__(256) void xw1_kernel(const float* __restrict__ X,
                                                  const float* __restrict__ W1,
                                                  float* __restrict__ B1) {
    __shared__ float sX[16 * 132];
    __shared__ float sW[128 * 16];
    const int t = threadIdx.x;
    const int row0 = blockIdx.x * 16;

    const float4* W4 = (const float4*)W1;
    float4* sW4 = (float4*)sW;
    for (int i = t; i < 512; i += 256) sW4[i] = W4[i];

    const float4* X4 = (const float4*)(X + (size_t)row0 * DIN);
    for (int i4 = t; i4 < 512; i4 += 256) {
        float4 v = X4[i4];
        int i = i4 * 4;
        int r = i >> 7, k = i & 127;
        float* dst = &sX[r * 132 + k];
        dst[0] = v.x; dst[1] = v.y; dst[2] = v.z; dst[3] = v.w;
    }
    __syncthreads();

    const int r = t >> 4, c = t & 15;
    float acc = 0.f;
#pragma unroll 16
    for (int k = 0; k < DIN; ++k)
        acc = fmaf(sX[r * 132 + k], sW[k * 16 + c], acc);
    B1[(size_t)(row0 + r) * DH + c] = acc;
}

// float4 component extract — folds to a register pick under full unroll.
__device__ __forceinline__ float f4c(const float4 v, int q) {
    return q == 0 ? v.x : q == 1 ? v.y : q == 2 ? v.z : v.w;
}

// ---------------------------------------------------------------------------
// Kernel 2: G = relu(A @ B1 + b1) @ W2    [N,4]
// Barrier-free, LDS-free. 256 thr = 4 waves; 16 rows/block (4 rows/wave).
// Lane owns 4 contiguous columns (j0 = jt + 4*lane):
//   - A loads are float4 (global_load_dwordx4, 1 KiB / wave instruction)
//   - B1 rows (64 B each) read straight from L1/L2 (B1 = 1 MiB, cache-hot)
// No __syncthreads in the hot loop -> no vmcnt(0) barrier drains; waves
// free-run and keep dwordx4 loads continuously in flight.
// ---------------------------------------------------------------------------
__global__ __launch_bounds__(256) void layer1_kernel(const float* __restrict__ A,
                                                     const float* __restrict__ B1,
                                                     const float* __restrict__ bias1,
                                                     const float* __restrict__ W2,
                                                     float* __restrict__ G) {
    const int t = threadIdx.x;
    const int lane = t & 63;
    const int wave = t >> 6;
    const int row0 = blockIdx.x * 16 + wave * 4;
    const float* A0 = A + (size_t)row0 * NN;

    float acc[4][16];
#pragma unroll
    for (int r = 0; r < 4; ++r)
#pragma unroll
        for (int c = 0; c < 16; ++c) acc[r][c] = 0.f;

    for (int jt = 0; jt < NN; jt += 256) {
        const int j0 = jt + lane * 4;

        float4 a[4];
#pragma unroll
        for (int r = 0; r < 4; ++r)
            a[r] = *(const float4*)(A0 + (size_t)r * NN + j0);

        // lane's 4 B1 rows are 256 contiguous bytes: Brow[0..15] float4s
        const float4* Brow = (const float4*)(B1 + (size_t)j0 * DH);

#pragma unroll
        for (int q = 0; q < 4; ++q) {
#pragma unroll
            for (int c4 = 0; c4 < 4; ++c4) {
                const float4 b = Brow[q * 4 + c4];
#pragma unroll
                for (int r = 0; r < 4; ++r) {
                    const float av = f4c(a[r], q);
                    acc[r][c4 * 4 + 0] = fmaf(av, b.x, acc[r][c4 * 4 + 0]);
                    acc[r][c4 * 4 + 1] = fmaf(av, b.y, acc[r][c4 * 4 + 1]);
                    acc[r][c4 * 4 + 2] = fmaf(av, b.z, acc[r][c4 * 4 + 2]);
                    acc[r][c4 * 4 + 3] = fmaf(av, b.w, acc[r][c4 * 4 + 3]);
                }
            }
        }
    }

    // cross-lane butterfly: every lane ends with the full row sums
#pragma unroll
    for (int r = 0; r < 4; ++r)
#pragma unroll
        for (int c = 0; c < 16; ++c) {
#pragma unroll
            for (int off = 32; off > 0; off >>= 1)
                acc[r][c] += __shfl_xor(acc[r][c], off, 64);
        }

    // epilogue: h = relu(acc + b1); g = h @ W2; lane 0 writes float4/row
#pragma unroll
    for (int r = 0; r < 4; ++r) {
        float g0 = 0.f, g1 = 0.f, g2 = 0.f, g3 = 0.f;
#pragma unroll
        for (int c = 0; c < 16; ++c) {
            float h = acc[r][c] + bias1[c];
            h = h > 0.f ? h : 0.f;
            const float4 w = *(const float4*)&W2[c * 4];
            g0 = fmaf(h, w.x, g0);
            g1 = fmaf(h, w.y, g1);
            g2 = fmaf(h, w.z, g2);
            g3 = fmaf(h, w.w, g3);
        }
        if (lane == 0)
            *(float4*)&G[(size_t)(row0 + r) * DOUT] = make_float4(g0, g1, g2, g3);
    }
}

// ---------------------------------------------------------------------------
// Kernel 3: out = A @ G + b2   [N,4]
// Same barrier-free structure. G rows are exactly one float4; a lane's 4
// rows are 64 contiguous bytes, L1/L2-resident (G = 256 KiB total).
// ---------------------------------------------------------------------------
__global__ __launch_bounds__(256) void layer2_kernel(const float* __restrict__ A,
                                                     const float* __restrict__ G,
                                                     const float* __restrict__ bias2,
                                                     float* __restrict__ out) {
    const int t = threadIdx.x;
    const int lane = t & 63;
    const int wave = t >> 6;
    const int row0 = blockIdx.x * 16 + wave * 4;
    const float* A0 = A + (size_t)row0 * NN;

    float acc[4][4];
#pragma unroll
    for (int r = 0; r < 4; ++r)
#pragma unroll
        for (int d = 0; d < 4; ++d) acc[r][d] = 0.f;

#pragma unroll 2
    for (int jt = 0; jt < NN; jt += 256) {
        const int j0 = jt + lane * 4;

        float4 a[4];
#pragma unroll
        for (int r = 0; r < 4; ++r)
            a[r] = *(const float4*)(A0 + (size_t)r * NN + j0);

        const float4* Grow = (const float4*)(G + (size_t)j0 * DOUT);

#pragma unroll
        for (int q = 0; q < 4; ++q) {
            const float4 g = Grow[q];
#pragma unroll
            for (int r = 0; r < 4; ++r) {
                const float av = f4c(a[r], q);
                acc[r][0] = fmaf(av, g.x, acc[r][0]);
                acc[r][1] = fmaf(av, g.y, acc[r][1]);
                acc[r][2] = fmaf(av, g.z, acc[r][2]);
                acc[r][3] = fmaf(av, g.w, acc[r][3]);
            }
        }
    }

#pragma unroll
    for (int r = 0; r < 4; ++r)
#pragma unroll
        for (int d = 0; d < 4; ++d) {
#pragma unroll
            for (int off = 32; off > 0; off >>= 1)
                acc[r][d] += __shfl_xor(acc[r][d], off, 64);
        }

    if (lane == 0) {
#pragma unroll
        for (int r = 0; r < 4; ++r) {
            float4 o = make_float4(acc[r][0] + bias2[0], acc[r][1] + bias2[1],
                                   acc[r][2] + bias2[2], acc[r][3] + bias2[3]);
            *(float4*)&out[(size_t)(row0 + r) * DOUT] = o;
        }
    }
}

extern "C" void kernel_launch(void* const* d_in, const int* in_sizes, int n_in,
                              void* d_out, int out_size, void* d_ws, size_t ws_size,
                              hipStream_t stream) {
    const float* A     = (const float*)d_in[0];   // [16384,16384]
    const float* X     = (const float*)d_in[1];   // [16384,128]
    const float* W1    = (const float*)d_in[2];   // [128,16]
    const float* bias1 = (const float*)d_in[3];   // [16]
    const float* W2    = (const float*)d_in[4];   // [16,4]
    const float* bias2 = (const float*)d_in[5];   // [4]
    float* out = (float*)d_out;                   // [16384,4]

    float* B1 = (float*)d_ws;                     // [16384,16] = 1 MiB
    float* G  = B1 + (size_t)NN * DH;             // [16384,4]  = 256 KiB

    xw1_kernel<<<NN / 16, 256, 0, stream>>>(X, W1, B1);
    layer1_kernel<<<NN / 16, 256, 0, stream>>>(A, B1, bias1, W2, G);
    layer2_kernel<<<NN / 16, 256, 0, stream>>>(A, G, bias2, out);
}